// Round 12
// baseline (827.414 us; speedup 1.0000x reference)
//
#include <hip/hip_runtime.h>

// Sizes (fixed): B=16, CIN=512, COUT=512, K=3, H=W=64, STYLE=512, BASIS=8, DIRS=8
// Workspace layout (bytes):
//  xp   (NHWC padded bf16 [16][66][66][512])  @ 0          : 71,368,704
//  wgt  (bf16 [16][9][512][512], NO demod)    @ 71,368,704 : 75,497,472
//  G    (36 floats, padded)                   @ 146,866,176: 256
//  camp ([16][8] f32)                         @ 146,866,432: 512
//  smod ([16][512] f32)                       @ 146,866,944: 32,768
//  demod([16][512] f32)                       @ 146,899,712: 32,768

typedef __attribute__((ext_vector_type(8))) short bf16x8;
typedef __attribute__((ext_vector_type(4))) float f32x4;

__device__ __forceinline__ unsigned short f2bf(float f) {
  unsigned u = __float_as_uint(f);
  return (unsigned short)((u + 0x7FFFu + ((u >> 16) & 1u)) >> 16);
}

__device__ __forceinline__ void gl_lds16(const void* g, void* l) {
  __builtin_amdgcn_global_load_lds(
      (const __attribute__((address_space(1))) void*)g,
      (__attribute__((address_space(3))) void*)l, 16, 0, 0);
}

__device__ __forceinline__ void vm_wait0() {
  asm volatile("s_waitcnt vmcnt(0)" ::: "memory");
}

// ---- K1: pad + NCHW f32 -> NHWC bf16, borders zeroed in-kernel ----
__global__ __launch_bounds__(256) void k_pad(const float* __restrict__ x,
                                             unsigned short* __restrict__ xp) {
  const int bx = blockIdx.x;
  const int b   = bx >> 9;
  const int rem = bx & 511;
  const int y   = rem >> 3;
  const int cb  = rem & 7;
  const int t = threadIdx.x;
  __shared__ float tile[64][65];
  const float* src = x + ((size_t)(b * 512 + cb * 64) * 4096) + y * 64;
#pragma unroll
  for (int r = 0; r < 4; ++r) {
    int idx = r * 256 + t;
    int ch = idx >> 4;
    int xq = (idx & 15) << 2;
    float4 v = *(const float4*)(src + (size_t)ch * 4096 + xq);
    tile[ch][xq + 0] = v.x; tile[ch][xq + 1] = v.y;
    tile[ch][xq + 2] = v.z; tile[ch][xq + 3] = v.w;
  }
  const uint4 z4 = {0u, 0u, 0u, 0u};
  if (t < 16) {
    const int side = t >> 3;
    const int lo = (t & 7) * 8;
    unsigned short* p =
        xp + (((size_t)(b * 66 + y + 1) * 66 + side * 65) * 512 + cb * 64 + lo);
    *(uint4*)p = z4;
  }
  if (y == 0 || y == 63) {
    const int row = (y == 0) ? 0 : 65;
    for (int idx = t; idx < 528; idx += 256) {
      const int c = idx >> 3;
      const int lo = (idx & 7) * 8;
      unsigned short* p =
          xp + (((size_t)(b * 66 + row) * 66 + c) * 512 + cb * 64 + lo);
      *(uint4*)p = z4;
    }
  }
  __syncthreads();
  const int col = t >> 2;
  const int q = t & 3;
  union { unsigned short u16[16]; uint4 v[2]; } pk;
#pragma unroll
  for (int j = 0; j < 16; ++j) pk.u16[j] = f2bf(tile[q * 16 + j][col]);
  unsigned short* dst =
      xp + (((size_t)(b * 66 + y + 1) * 66 + col + 1) * 512 + cb * 64 + q * 16);
  *(uint4*)dst = pk.v[0];
  *(uint4*)(dst + 8) = pk.v[1];
}

// ---- K2: s[b][i] = style[b] . mod_w[i] + mod_b[i] ----
__global__ __launch_bounds__(256) void k_mod(const float* __restrict__ style,
                                             const float* __restrict__ mod_w,
                                             const float* __restrict__ mod_b,
                                             float* __restrict__ smod) {
  const int b = blockIdx.x;
  __shared__ float st[512];
  for (int d = threadIdx.x; d < 512; d += 256) st[d] = style[b * 512 + d];
  __syncthreads();
  for (int i = threadIdx.x; i < 512; i += 256) {
    const float* wr = mod_w + (size_t)i * 512;
    float acc = 0.f;
#pragma unroll 4
    for (int d = 0; d < 512; d += 4) {
      float4 wv = *(const float4*)(wr + d);
      acc += wv.x * st[d] + wv.y * st[d + 1] + wv.z * st[d + 2] + wv.w * st[d + 3];
    }
    smod[b * 512 + i] = acc + mod_b[i];
  }
}

// ---- K3: Gram matrix of the 8 basis vectors (upper-tri, 36 entries) ----
__global__ __launch_bounds__(256, 3) void k_gram(const float* __restrict__ bv,
                                                 float* __restrict__ G) {
  const int P4 = 589824;  // (512*512*9)/4
  float a[36];
#pragma unroll
  for (int c = 0; c < 36; ++c) a[c] = 0.f;
  const float4* bv4 = (const float4*)bv;
  for (int p = blockIdx.x * 256 + threadIdx.x; p < P4; p += gridDim.x * 256) {
    float4 v[8];
#pragma unroll
    for (int k = 0; k < 8; ++k) v[k] = bv4[(size_t)k * P4 + p];
    int c = 0;
#pragma unroll
    for (int i = 0; i < 8; ++i)
#pragma unroll
      for (int j = i; j < 8; ++j) {
        a[c] += v[i].x * v[j].x + v[i].y * v[j].y + v[i].z * v[j].z +
                v[i].w * v[j].w;
        ++c;
      }
  }
#pragma unroll
  for (int c = 0; c < 36; ++c)
#pragma unroll
    for (int off = 32; off > 0; off >>= 1) a[c] += __shfl_down(a[c], off);
  __shared__ float red[4][36];
  const int wv = threadIdx.x >> 6;
  if ((threadIdx.x & 63) == 0)
#pragma unroll
    for (int c = 0; c < 36; ++c) red[wv][c] = a[c];
  __syncthreads();
  if (threadIdx.x < 36)
    atomicAdd(&G[threadIdx.x], red[0][threadIdx.x] + red[1][threadIdx.x] +
                                   red[2][threadIdx.x] + red[3][threadIdx.x]);
}

// ---- K4: camp[b][k] = coef[b][k] * shift_b / max(||delta||,1e-12) via Gram ----
__global__ void k_amp(const float* __restrict__ shifts_coords,
                      const float* __restrict__ batch_shifts,
                      const int* __restrict__ dirs, const float* __restrict__ G,
                      float* __restrict__ camp) {
  const int b = threadIdx.x;
  if (b < 16) {
    const int dir = dirs[b];
    float c[8];
    for (int k = 0; k < 8; ++k) c[k] = shifts_coords[dir * 8 + k];
    float n2 = 0.f;
    int idx = 0;
    for (int i = 0; i < 8; ++i)
      for (int j = i; j < 8; ++j) {
        float g = G[idx++];
        n2 += (i == j) ? c[i] * c[i] * g : 2.f * c[i] * c[j] * g;
      }
    float nrm = sqrtf(fmaxf(n2, 0.f));
    float amp = batch_shifts[b] / fmaxf(nrm, 1e-12f);
    for (int k = 0; k < 8; ++k) camp[b * 8 + k] = c[k] * amp;
  }
}

// ---- K5: modulated weights -> bf16 [b][kk][o][i]; demod table separate ----
__global__ __launch_bounds__(512) void k_weights(const float* __restrict__ weight,
                                                 const float* __restrict__ bv,
                                                 const float* __restrict__ smod,
                                                 const float* __restrict__ camp,
                                                 unsigned short* __restrict__ wgt,
                                                 float* __restrict__ demod) {
  const int o = blockIdx.x;
  const int i = threadIdx.x;
  __shared__ float cl[128];
  __shared__ float red[8][16];
  if (threadIdx.x < 128) cl[threadIdx.x] = camp[threadIdx.x];
  __syncthreads();
  const float scl = 0.014731391274719738f;  // 1/sqrt(512*9)
  float sm[16];
#pragma unroll
  for (int b = 0; b < 16; ++b) sm[b] = smod[b * 512 + i] * scl;
  float ssq[16];
#pragma unroll
  for (int b = 0; b < 16; ++b) ssq[b] = 0.f;
  const size_t base = ((size_t)o * 512 + i) * 9;
#pragma unroll
  for (int g = 0; g < 3; ++g) {
    float w[3], v[8][3];
#pragma unroll
    for (int q = 0; q < 3; ++q) w[q] = weight[base + g * 3 + q];
#pragma unroll
    for (int k = 0; k < 8; ++k)
#pragma unroll
      for (int q = 0; q < 3; ++q)
        v[k][q] = bv[(size_t)k * 2359296 + base + g * 3 + q];
#pragma unroll
    for (int b = 0; b < 16; ++b) {
#pragma unroll
      for (int q = 0; q < 3; ++q) {
        float d = w[q];
#pragma unroll
        for (int k = 0; k < 8; ++k) d = fmaf(cl[b * 8 + k], v[k][q], d);
        float wv = d * sm[b];
        ssq[b] = fmaf(wv, wv, ssq[b]);
        wgt[(((size_t)(b * 9 + g * 3 + q) * 512 + o) << 9) + i] = f2bf(wv);
      }
    }
  }
#pragma unroll
  for (int b = 0; b < 16; ++b)
#pragma unroll
    for (int off = 32; off > 0; off >>= 1) ssq[b] += __shfl_down(ssq[b], off);
  const int wv_ = threadIdx.x >> 6;
  if ((threadIdx.x & 63) == 0)
#pragma unroll
    for (int b = 0; b < 16; ++b) red[wv_][b] = ssq[b];
  __syncthreads();
  if (threadIdx.x < 16) {
    float s = 0.f;
#pragma unroll
    for (int wq = 0; wq < 8; ++wq) s += red[wq][threadIdx.x];
    demod[threadIdx.x * 512 + o] = rsqrtf(s + 1e-8f);
  }
}

// ---- K6: grouped conv, 256x256 tile, BK=32, A DIRECT global->VGPR
// (software-pipelined 1 tile ahead, two named reg sets), B via LDS
// (16KB/tile, 2-buf 32KB, proven 64B-row swizzle). Per tile/wave:
// 4 ds_read + 8 global_load + 2 gl_lds + 32 MFMA + vmcnt(0) + 1 barrier.
// A loads: saddr + 32-bit voffset; lanes of one load cover 16 o-rows x
// full 64B lines (ls=0..3 slots complete each line).
__global__ __launch_bounds__(512, 2) void k_conv(
    const unsigned short* __restrict__ xp, const unsigned short* __restrict__ wgt,
    const float* __restrict__ demod, float* __restrict__ out) {
  extern __shared__ unsigned char smem[];  // 32768 = buf0 16K | buf1 16K
  const int tid = threadIdx.x;
  const int l = tid & 63;
  const int w = tid >> 6;
  const int wo = w >> 2;  // 0..1 -> o rows wo*128..+127
  const int wn = w & 3;   // 0..3 -> px  wn*64..+63
  const int lq = l & 15;
  const int ls = l >> 4;

  // XCD-bijective swizzle: 512 blocks, 64/XCD = 2 full samples per XCD
  const int bid = blockIdx.x;
  const int bz = (bid & 7) * 64 + (bid >> 3);
  const int b = bz >> 5;
  const int tt = bz & 31;
  const int o0 = (tt >> 4) << 8;  // 0 / 256
  const int tn = tt & 15;
  const int n0 = tn << 8;  // 256-px tile (4 rows of 64)
  const int y0 = tn << 2;

  // A: direct per-lane voffsets (base folded: wgt + b,o0)
  const char* wgtA = (const char*)wgt + ((size_t)(b * 9) << 19) +
                     ((size_t)o0 << 10);
  unsigned a_voff[8];
#pragma unroll
  for (int mi = 0; mi < 8; ++mi)
    a_voff[mi] = ((unsigned)(wo * 128 + mi * 16 + lq) << 10) + (ls << 4);

  // B staging: 2 chunks/thread; 256 px-rows x 64B; slot' = slot ^ ((row>>1)&3)
  unsigned bSrc[2];
#pragma unroll
  for (int r = 0; r < 2; ++r) {
    const int idx = r * 512 + tid;
    const int row = idx >> 2;
    const int sl = (idx & 3) ^ ((row >> 1) & 3);
    bSrc[r] = ((unsigned)((b * 66 + y0 + (row >> 6)) * 66 + (row & 63)) << 10) +
              sl * 16;
  }
  // B read offsets (within a 16KB buffer)
  unsigned bRd[4];
#pragma unroll
  for (int ni = 0; ni < 4; ++ni) {
    const int row = wn * 64 + ni * 16 + lq;
    bRd[ni] = row * 64 + ((ls ^ ((row >> 1) & 3)) << 4);
  }

  const char* xpc = (const char*)xp;

  f32x4 acc[8][4];
  const f32x4 zz = {0.f, 0.f, 0.f, 0.f};
#pragma unroll
  for (int mi = 0; mi < 8; ++mi)
#pragma unroll
    for (int ni = 0; ni < 4; ++ni) acc[mi][ni] = zz;
  bf16x8 afA[8], afB[8], bf[4];

  // prologue: stage B(0) into buf0; load afA(0); drain; publish
  {
#pragma unroll
    for (int r = 0; r < 2; ++r)
      gl_lds16(xpc + bSrc[r], smem + (r * 512 + tid) * 16);
#pragma unroll
    for (int mi = 0; mi < 8; ++mi)
      afA[mi] = *(const bf16x8*)(wgtA + a_voff[mi]);
  }
  vm_wait0();
  __builtin_amdgcn_s_barrier();
  __builtin_amdgcn_sched_barrier(0);

  auto body = [&](int s, bf16x8 (&afC)[8], bf16x8 (&afN)[8], int par) {
    const unsigned char* lB = smem + (par ? 16384 : 0);
    unsigned char* wB = smem + (par ? 0 : 16384);
    // B fragments for tile s
#pragma unroll
    for (int ni = 0; ni < 4; ++ni)
      bf[ni] = *(const bf16x8*)(lB + bRd[ni]);
    // prefetch tile s+1: A->regs, B->other LDS buffer
    if (s < 143) {
      const int s1 = s + 1;
      const int kk1 = s1 >> 4;
      const int is1 = s1 & 15;
      const char* aT = wgtA + ((size_t)kk1 << 19) + ((unsigned)is1 << 6);
#pragma unroll
      for (int mi = 0; mi < 8; ++mi)
        afN[mi] = *(const bf16x8*)(aT + a_voff[mi]);
      const int ky1 = kk1 / 3;
      const int kx1 = kk1 - ky1 * 3;
      const unsigned tOff =
          ((unsigned)(ky1 * 66 + kx1) << 10) + ((unsigned)is1 << 6);
#pragma unroll
      for (int r = 0; r < 2; ++r)
        gl_lds16(xpc + bSrc[r] + tOff, wB + (r * 512 + tid) * 16);
    }
    __builtin_amdgcn_s_setprio(1);
#pragma unroll
    for (int mi = 0; mi < 8; ++mi)
#pragma unroll
      for (int ni = 0; ni < 4; ++ni)
        acc[mi][ni] = __builtin_amdgcn_mfma_f32_16x16x32_bf16(
            afC[mi], bf[ni], acc[mi][ni], 0, 0, 0);
    __builtin_amdgcn_s_setprio(0);
    __builtin_amdgcn_sched_barrier(0);
    vm_wait0();  // afN landed + B(s+1) in LDS (before barrier!)
    __builtin_amdgcn_s_barrier();
    __builtin_amdgcn_sched_barrier(0);
  };

#pragma unroll 1
  for (int s = 0; s < 144; s += 2) {
    body(s, afA, afB, 0);
    body(s + 1, afB, afA, 1);
  }

  float* outb = out + (size_t)(b * 512 + o0) * 4096 + n0;
#pragma unroll
  for (int mi = 0; mi < 8; ++mi) {
    const int orow = wo * 128 + mi * 16 + ls * 4;
    float dm[4];
#pragma unroll
    for (int r = 0; r < 4; ++r) dm[r] = demod[b * 512 + o0 + orow + r];
#pragma unroll
    for (int ni = 0; ni < 4; ++ni) {
      const int pix = wn * 64 + ni * 16 + lq;
#pragma unroll
      for (int r = 0; r < 4; ++r)
        outb[(size_t)(orow + r) * 4096 + pix] = acc[mi][ni][r] * dm[r];
    }
  }
}

extern "C" void kernel_launch(void* const* d_in, const int* in_sizes, int n_in,
                              void* d_out, int out_size, void* d_ws,
                              size_t ws_size, hipStream_t stream) {
  const float* x      = (const float*)d_in[0];
  const float* style  = (const float*)d_in[1];
  const float* weight = (const float*)d_in[2];
  const float* mod_w  = (const float*)d_in[3];
  const float* mod_b  = (const float*)d_in[4];
  const float* bv     = (const float*)d_in[5];
  const float* sc     = (const float*)d_in[6];
  const float* bsh    = (const float*)d_in[7];
  const int*   bdir   = (const int*)d_in[8];
  float* out = (float*)d_out;

  char* ws = (char*)d_ws;
  unsigned short* xp  = (unsigned short*)(ws);
  unsigned short* wgt = (unsigned short*)(ws + 71368704);
  float* G     = (float*)(ws + 146866176);
  float* camp  = (float*)(ws + 146866432);
  float* smod  = (float*)(ws + 146866944);
  float* demod = (float*)(ws + 146899712);

  hipFuncSetAttribute((const void*)k_conv,
                      hipFuncAttributeMaxDynamicSharedMemorySize, 32768);

  hipMemsetAsync(G, 0, 256, stream);
  k_pad<<<8192, 256, 0, stream>>>(x, xp);
  k_mod<<<16, 256, 0, stream>>>(style, mod_w, mod_b, smod);
  k_gram<<<1024, 256, 0, stream>>>(bv, G);
  k_amp<<<1, 64, 0, stream>>>(sc, bsh, bdir, G, camp);
  k_weights<<<512, 512, 0, stream>>>(weight, bv, smod, camp, wgt, demod);
  k_conv<<<512, 512, 32768, stream>>>(xp, wgt, demod, out);
}

// Round 13
// 415.975 us; speedup vs baseline: 1.9891x; 1.9891x over previous
//
#include <hip/hip_runtime.h>

// Sizes (fixed): B=16, CIN=512, COUT=512, K=3, H=W=64, STYLE=512, BASIS=8, DIRS=8
// Workspace layout (bytes):
//  xp   (NHWC padded bf16 [16][66][66][512])  @ 0          : 71,368,704
//  wgt  (bf16 [16][9][512][512], NO demod)    @ 71,368,704 : 75,497,472
//  G    (36 floats, padded)                   @ 146,866,176: 256
//  smod ([16][512] f32)                       @ 146,866,944: 32,768
//  demod([16][512] f32)                       @ 146,899,712: 32,768

typedef __attribute__((ext_vector_type(8))) short bf16x8;
typedef __attribute__((ext_vector_type(4))) float f32x4;
typedef float f32x4u __attribute__((ext_vector_type(4), aligned(4)));

__device__ __forceinline__ unsigned short f2bf(float f) {
  unsigned u = __float_as_uint(f);
  return (unsigned short)((u + 0x7FFFu + ((u >> 16) & 1u)) >> 16);
}

__device__ __forceinline__ void gl_lds16(const void* g, void* l) {
  __builtin_amdgcn_global_load_lds(
      (const __attribute__((address_space(1))) void*)g,
      (__attribute__((address_space(3))) void*)l, 16, 0, 0);
}

template <int N> __device__ __forceinline__ void vm_wait() {
  if constexpr (N == 8) asm volatile("s_waitcnt vmcnt(8)" ::: "memory");
  else if constexpr (N == 0) asm volatile("s_waitcnt vmcnt(0)" ::: "memory");
}

// ---- K1: pad + NCHW f32 -> NHWC bf16, borders zeroed in-kernel ----
__global__ __launch_bounds__(256) void k_pad(const float* __restrict__ x,
                                             unsigned short* __restrict__ xp) {
  const int bx = blockIdx.x;
  const int b   = bx >> 9;
  const int rem = bx & 511;
  const int y   = rem >> 3;
  const int cb  = rem & 7;
  const int t = threadIdx.x;
  __shared__ float tile[64][65];
  const float* src = x + ((size_t)(b * 512 + cb * 64) * 4096) + y * 64;
#pragma unroll
  for (int r = 0; r < 4; ++r) {
    int idx = r * 256 + t;
    int ch = idx >> 4;
    int xq = (idx & 15) << 2;
    float4 v = *(const float4*)(src + (size_t)ch * 4096 + xq);
    tile[ch][xq + 0] = v.x; tile[ch][xq + 1] = v.y;
    tile[ch][xq + 2] = v.z; tile[ch][xq + 3] = v.w;
  }
  const uint4 z4 = {0u, 0u, 0u, 0u};
  if (t < 16) {
    const int side = t >> 3;
    const int lo = (t & 7) * 8;
    unsigned short* p =
        xp + (((size_t)(b * 66 + y + 1) * 66 + side * 65) * 512 + cb * 64 + lo);
    *(uint4*)p = z4;
  }
  if (y == 0 || y == 63) {
    const int row = (y == 0) ? 0 : 65;
    for (int idx = t; idx < 528; idx += 256) {
      const int c = idx >> 3;
      const int lo = (idx & 7) * 8;
      unsigned short* p =
          xp + (((size_t)(b * 66 + row) * 66 + c) * 512 + cb * 64 + lo);
      *(uint4*)p = z4;
    }
  }
  __syncthreads();
  const int col = t >> 2;
  const int q = t & 3;
  union { unsigned short u16[16]; uint4 v[2]; } pk;
#pragma unroll
  for (int j = 0; j < 16; ++j) pk.u16[j] = f2bf(tile[q * 16 + j][col]);
  unsigned short* dst =
      xp + (((size_t)(b * 66 + y + 1) * 66 + col + 1) * 512 + cb * 64 + q * 16);
  *(uint4*)dst = pk.v[0];
  *(uint4*)(dst + 8) = pk.v[1];
}

// ---- K2: s[b][i] = style[b] . mod_w[i] + mod_b[i] ----
__global__ __launch_bounds__(256) void k_mod(const float* __restrict__ style,
                                             const float* __restrict__ mod_w,
                                             const float* __restrict__ mod_b,
                                             float* __restrict__ smod) {
  const int b = blockIdx.x;
  __shared__ float st[512];
  for (int d = threadIdx.x; d < 512; d += 256) st[d] = style[b * 512 + d];
  __syncthreads();
  for (int i = threadIdx.x; i < 512; i += 256) {
    const float* wr = mod_w + (size_t)i * 512;
    float acc = 0.f;
#pragma unroll 4
    for (int d = 0; d < 512; d += 4) {
      float4 wv = *(const float4*)(wr + d);
      acc += wv.x * st[d] + wv.y * st[d + 1] + wv.z * st[d + 2] + wv.w * st[d + 3];
    }
    smod[b * 512 + i] = acc + mod_b[i];
  }
}

// ---- K3: Gram matrix of the 8 basis vectors (upper-tri, 36 entries) ----
__global__ __launch_bounds__(256, 3) void k_gram(const float* __restrict__ bv,
                                                 float* __restrict__ G) {
  const int P4 = 589824;  // (512*512*9)/4
  float a[36];
#pragma unroll
  for (int c = 0; c < 36; ++c) a[c] = 0.f;
  const float4* bv4 = (const float4*)bv;
  for (int p = blockIdx.x * 256 + threadIdx.x; p < P4; p += gridDim.x * 256) {
    float4 v[8];
#pragma unroll
    for (int k = 0; k < 8; ++k) v[k] = bv4[(size_t)k * P4 + p];
    int c = 0;
#pragma unroll
    for (int i = 0; i < 8; ++i)
#pragma unroll
      for (int j = i; j < 8; ++j) {
        a[c] += v[i].x * v[j].x + v[i].y * v[j].y + v[i].z * v[j].z +
                v[i].w * v[j].w;
        ++c;
      }
  }
#pragma unroll
  for (int c = 0; c < 36; ++c)
#pragma unroll
    for (int off = 32; off > 0; off >>= 1) a[c] += __shfl_down(a[c], off);
  __shared__ float red[4][36];
  const int wv = threadIdx.x >> 6;
  if ((threadIdx.x & 63) == 0)
#pragma unroll
    for (int c = 0; c < 36; ++c) red[wv][c] = a[c];
  __syncthreads();
  if (threadIdx.x < 36)
    atomicAdd(&G[threadIdx.x], red[0][threadIdx.x] + red[1][threadIdx.x] +
                                   red[2][threadIdx.x] + red[3][threadIdx.x]);
}

// ---- K5: modulated weights -> bf16 [b][kk][o][i]; camp folded in-block;
// vectorized 9-float row loads (2x float4(align4) + 1 scalar). ----
__global__ __launch_bounds__(512, 2) void k_weights(
    const float* __restrict__ weight, const float* __restrict__ bv,
    const float* __restrict__ smod, const float* __restrict__ G,
    const float* __restrict__ shifts_coords,
    const float* __restrict__ batch_shifts, const int* __restrict__ dirs,
    unsigned short* __restrict__ wgt, float* __restrict__ demod) {
  const int o = blockIdx.x;
  const int i = threadIdx.x;
  __shared__ float cl[128];   // camp[16][8]
  __shared__ float red[8][16];
  if (threadIdx.x < 16) {     // fold of old k_amp (per-block recompute)
    const int b = threadIdx.x;
    const int dir = dirs[b];
    float c[8];
#pragma unroll
    for (int k = 0; k < 8; ++k) c[k] = shifts_coords[dir * 8 + k];
    float n2 = 0.f;
    int idx = 0;
#pragma unroll
    for (int ii = 0; ii < 8; ++ii)
#pragma unroll
      for (int j = ii; j < 8; ++j) {
        float g = G[idx++];
        n2 += (ii == j) ? c[ii] * c[ii] * g : 2.f * c[ii] * c[j] * g;
      }
    const float amp =
        batch_shifts[b] / fmaxf(sqrtf(fmaxf(n2, 0.f)), 1e-12f);
#pragma unroll
    for (int k = 0; k < 8; ++k) cl[b * 8 + k] = c[k] * amp;
  }
  __syncthreads();
  const float scl = 0.014731391274719738f;  // 1/sqrt(512*9)
  const size_t base = ((size_t)o * 512 + i) * 9;
  // vectorized row loads: weight row + 8 bv rows (9 floats each)
  float w9[9], v9[8][9];
  {
    f32x4u a = *(const f32x4u*)(weight + base);
    f32x4u c = *(const f32x4u*)(weight + base + 4);
    w9[0] = a.x; w9[1] = a.y; w9[2] = a.z; w9[3] = a.w;
    w9[4] = c.x; w9[5] = c.y; w9[6] = c.z; w9[7] = c.w;
    w9[8] = weight[base + 8];
  }
#pragma unroll
  for (int k = 0; k < 8; ++k) {
    const float* pk_ = bv + (size_t)k * 2359296 + base;
    f32x4u a = *(const f32x4u*)(pk_);
    f32x4u c = *(const f32x4u*)(pk_ + 4);
    v9[k][0] = a.x; v9[k][1] = a.y; v9[k][2] = a.z; v9[k][3] = a.w;
    v9[k][4] = c.x; v9[k][5] = c.y; v9[k][6] = c.z; v9[k][7] = c.w;
    v9[k][8] = pk_[8];
  }
  float ssq[16];
#pragma unroll
  for (int b = 0; b < 16; ++b) ssq[b] = 0.f;
#pragma unroll
  for (int b = 0; b < 16; ++b) {
    const float sm_b = smod[b * 512 + i] * scl;
#pragma unroll
    for (int kk = 0; kk < 9; ++kk) {
      float d = w9[kk];
#pragma unroll
      for (int k = 0; k < 8; ++k) d = fmaf(cl[b * 8 + k], v9[k][kk], d);
      const float wv = d * sm_b;
      ssq[b] = fmaf(wv, wv, ssq[b]);
      wgt[(((size_t)(b * 9 + kk) * 512 + o) << 9) + i] = f2bf(wv);
    }
  }
#pragma unroll
  for (int b = 0; b < 16; ++b)
#pragma unroll
    for (int off = 32; off > 0; off >>= 1) ssq[b] += __shfl_down(ssq[b], off);
  const int wv_ = threadIdx.x >> 6;
  if ((threadIdx.x & 63) == 0)
#pragma unroll
    for (int b = 0; b < 16; ++b) red[wv_][b] = ssq[b];
  __syncthreads();
  if (threadIdx.x < 16) {
    float s = 0.f;
#pragma unroll
    for (int wq = 0; wq < 8; ++wq) s += red[wq][threadIdx.x];
    demod[threadIdx.x * 512 + o] = rsqrtf(s + 1e-8f);
  }
}

// ---- K6: grouped conv, 256x256xBK64; 2 barriers/tile overlap schedule
// (exact R6 revert — best measured: 291 us, MfmaUtil 47.6%).
__global__ __launch_bounds__(512, 2) void k_conv(
    const unsigned short* __restrict__ xp, const unsigned short* __restrict__ wgt,
    const float* __restrict__ demod, float* __restrict__ out) {
  extern __shared__ unsigned char smem[];  // 131072: buf{0,1} x (A 32K | B 32K)
  const int tid = threadIdx.x;
  const int l = tid & 63;
  const int w = tid >> 6;
  const int wo = w >> 2;  // 0..1
  const int wn = w & 3;   // 0..3

  const int bid = blockIdx.x;
  const int bz = (bid & 7) * 64 + (bid >> 3);
  const int b = bz >> 5;
  const int tt = bz & 31;
  const int o0 = (tt >> 4) << 8;
  const int tn = tt & 15;
  const int n0 = tn << 8;
  const int y0 = tn << 2;

  int swzS[4];
  size_t aByte[4], pBase[4];
#pragma unroll
  for (int r = 0; r < 4; ++r) {
    const int idx = r * 512 + tid;
    const int row = idx >> 3;
    const int swz = ((idx & 7) << 4) ^ ((row & 7) << 4);
    swzS[r] = swz;
    aByte[r] = ((size_t)(o0 + row) << 10) + swz;
    pBase[r] = (size_t)(b * 66 + y0 + (row >> 6)) * 66 + (row & 63);
  }

  const char* wgtc = (const char*)wgt;
  const char* xpc = (const char*)xp;

  auto stage_all = [&](unsigned char* buf, int kt) {
    const int kk = kt >> 3;
    const int is = kt & 7;
    const int ky = kk / 3;
    const int kx = kk - ky * 3;
    const size_t aPlane = ((size_t)(b * 9 + kk) << 19) + ((size_t)is << 7);
    unsigned char* lA = buf;
    unsigned char* lB = buf + 32768;
#pragma unroll
    for (int r = 0; r < 4; ++r)
      gl_lds16(wgtc + aPlane + aByte[r], lA + (r * 512 + tid) * 16);
#pragma unroll
    for (int r = 0; r < 4; ++r)
      gl_lds16(xpc + (((pBase[r] + ky * 66 + kx) << 10) + ((size_t)is << 7) +
                      swzS[r]),
               lB + (r * 512 + tid) * 16);
  };

  f32x4 acc[8][4];
  const f32x4 zz = {0.f, 0.f, 0.f, 0.f};
#pragma unroll
  for (int mi = 0; mi < 8; ++mi)
#pragma unroll
    for (int ni = 0; ni < 4; ++ni) acc[mi][ni] = zz;
  bf16x8 af0[8], af1[8], bf0[4], bf1[4];

  auto rdA = [&](const unsigned char* lA, int MH, bf16x8 (&afx)[8]) {
#pragma unroll
    for (int mi = 0; mi < 4; ++mi)
#pragma unroll
      for (int ks = 0; ks < 2; ++ks) {
        const int row = MH * 128 + wo * 64 + mi * 16 + (l & 15);
        afx[mi * 2 + ks] = *(const bf16x8*)(
            lA + row * 128 + ((ks * 64 + ((l >> 4) << 4)) ^ ((row & 7) << 4)));
      }
  };
  auto rdB = [&](const unsigned char* lB, int NH, bf16x8 (&bfx)[4]) {
#pragma unroll
    for (int ni = 0; ni < 2; ++ni)
#pragma unroll
      for (int ks = 0; ks < 2; ++ks) {
        const int row = NH * 128 + wn * 32 + ni * 16 + (l & 15);
        bfx[ni * 2 + ks] = *(const bf16x8*)(
            lB + row * 128 + ((ks * 64 + ((l >> 4) << 4)) ^ ((row & 7) << 4)));
      }
  };
  auto mma = [&](int MH, int NH, bf16x8 (&afx)[8], bf16x8 (&bfx)[4]) {
    __builtin_amdgcn_s_setprio(1);
#pragma unroll
    for (int mi = 0; mi < 4; ++mi)
#pragma unroll
      for (int ni = 0; ni < 2; ++ni)
#pragma unroll
        for (int ks = 0; ks < 2; ++ks)
          acc[MH * 4 + mi][NH * 2 + ni] =
              __builtin_amdgcn_mfma_f32_16x16x32_bf16(
                  afx[mi * 2 + ks], bfx[ni * 2 + ks],
                  acc[MH * 4 + mi][NH * 2 + ni], 0, 0, 0);
    __builtin_amdgcn_s_setprio(0);
  };

  stage_all(smem, 0);
  stage_all(smem + 65536, 1);
  vm_wait<8>();
  __builtin_amdgcn_s_barrier();

  int cur = 0;
#pragma unroll 1
  for (int kt = 0; kt < 72; ++kt) {
    unsigned char* lA = smem + (cur << 16);
    unsigned char* lB = lA + 32768;
    rdA(lA, 0, af0);
    rdB(lB, 0, bf0);
    rdB(lB, 1, bf1);
    rdA(lA, 1, af1);
    mma(0, 0, af0, bf0);
    mma(0, 1, af0, bf1);
    asm volatile("s_waitcnt lgkmcnt(0)" ::: "memory");
    __builtin_amdgcn_sched_barrier(0);
    __builtin_amdgcn_s_barrier();  // BAR_A
    __builtin_amdgcn_sched_barrier(0);
    if (kt < 70) stage_all(lA, kt + 2);
    mma(1, 1, af1, bf1);
    mma(1, 0, af1, bf0);
    if (kt < 70) {
      vm_wait<8>();
      __builtin_amdgcn_s_barrier();  // BAR_B
      __builtin_amdgcn_sched_barrier(0);
    } else if (kt == 70) {
      vm_wait<0>();
      __builtin_amdgcn_s_barrier();
      __builtin_amdgcn_sched_barrier(0);
    }
    cur ^= 1;
  }

  float* outb = out + (size_t)(b * 512 + o0) * 4096 + n0;
#pragma unroll
  for (int mh = 0; mh < 2; ++mh)
#pragma unroll
    for (int mi = 0; mi < 4; ++mi) {
      const int orow = mh * 128 + wo * 64 + mi * 16 + ((l >> 4) << 2);
      float dm[4];
#pragma unroll
      for (int r = 0; r < 4; ++r) dm[r] = demod[b * 512 + o0 + orow + r];
#pragma unroll
      for (int nh = 0; nh < 2; ++nh)
#pragma unroll
        for (int ni = 0; ni < 2; ++ni) {
          const int pix = nh * 128 + wn * 32 + ni * 16 + (l & 15);
#pragma unroll
          for (int r = 0; r < 4; ++r)
            outb[(size_t)(orow + r) * 4096 + pix] =
                acc[mh * 4 + mi][nh * 2 + ni][r] * dm[r];
        }
    }
}

extern "C" void kernel_launch(void* const* d_in, const int* in_sizes, int n_in,
                              void* d_out, int out_size, void* d_ws,
                              size_t ws_size, hipStream_t stream) {
  const float* x      = (const float*)d_in[0];
  const float* style  = (const float*)d_in[1];
  const float* weight = (const float*)d_in[2];
  const float* mod_w  = (const float*)d_in[3];
  const float* mod_b  = (const float*)d_in[4];
  const float* bv     = (const float*)d_in[5];
  const float* sc     = (const float*)d_in[6];
  const float* bsh    = (const float*)d_in[7];
  const int*   bdir   = (const int*)d_in[8];
  float* out = (float*)d_out;

  char* ws = (char*)d_ws;
  unsigned short* xp  = (unsigned short*)(ws);
  unsigned short* wgt = (unsigned short*)(ws + 71368704);
  float* G     = (float*)(ws + 146866176);
  float* smod  = (float*)(ws + 146866944);
  float* demod = (float*)(ws + 146899712);

  hipFuncSetAttribute((const void*)k_conv,
                      hipFuncAttributeMaxDynamicSharedMemorySize, 131072);

  hipMemsetAsync(G, 0, 256, stream);
  k_pad<<<8192, 256, 0, stream>>>(x, xp);
  k_mod<<<16, 256, 0, stream>>>(style, mod_w, mod_b, smod);
  k_gram<<<1024, 256, 0, stream>>>(bv, G);
  k_weights<<<512, 512, 0, stream>>>(weight, bv, smod, G, sc, bsh, bdir, wgt,
                                     demod);
  k_conv<<<512, 512, 131072, stream>>>(xp, wgt, demod, out);
}